// Round 8
// baseline (271.531 us; speedup 1.0000x reference)
//
#include <hip/hip_runtime.h>
#include <math.h>

#define D 128
#define NNODES 8192
#define NEDGES 16384
#define NSTEMS 4096
#define NGRAPHS 256
#define NSTEPS 12
#define OPS 105
#define SLOPE 0.01f
#define IMT 32             // nodes per init-block
#define MTS 16             // nodes per step-block
#define NBS (NNODES / MTS) // 512 step blocks -> 2 blocks/CU, 4 waves/SIMD
#define LDA 136            // padded halfs per LDS row (h/m tiles)
#define LDA2 264           // padded halfs per LDS row (stem cat tile)
#define LDQ 40             // padded halfs per Qh row
#define LDH 132            // padded floats per Hs row

typedef _Float16 half_t;
typedef __attribute__((ext_vector_type(8))) _Float16 f16x8;
typedef __attribute__((ext_vector_type(4))) float f32x4;

__device__ __forceinline__ float leaky(float x) { return x > 0.f ? x : SLOPE * x; }
__device__ __forceinline__ float fast_sigmoid(float x) {
    return __builtin_amdgcn_rcpf(1.f + __expf(-x));
}
__device__ __forceinline__ float fast_tanh(float x) {
    float e = __expf(2.f * x);
    return 1.f - 2.f * __builtin_amdgcn_rcpf(e + 1.f);
}

// ---------------- setup: pack weights + transpose g1 + zero scratch ----------------
// B-frag 16x16x32: lane L supplies B[k = kt*32 + (L>>4)*8 + j][n = nt*16 + (L&15)], j=0..7.
__global__ void k_setup(
    const float* __restrict__ root, const float* __restrict__ wih,
    const float* __restrict__ whh, const float* __restrict__ bond,
    const float* __restrict__ sw1, const float* __restrict__ sw2,
    const float* __restrict__ sw3, const float* __restrict__ bw1,
    const float* __restrict__ bw2, const float* __restrict__ gw1,
    half_t* __restrict__ rootP, half_t* __restrict__ WihP,
    half_t* __restrict__ WhhP, half_t* __restrict__ bondTP,
    half_t* __restrict__ s1P, half_t* __restrict__ s2P, half_t* __restrict__ s3P,
    half_t* __restrict__ w1P, half_t* __restrict__ w2P, half_t* __restrict__ bondQP,
    float* __restrict__ g1T, int* __restrict__ zeroi) {
    int idx = blockIdx.x * 256 + threadIdx.x;
    int which = blockIdx.y;
    if (which == 10) {
        if (idx < 128 * 128) {
            int r = idx >> 7, c = idx & 127;
            g1T[c * 128 + r] = gw1[idx];
        }
        return;
    }
    if (which == 11) {
        if (idx < 2 * NNODES) zeroi[idx] = 0;
        return;
    }
    int KT = (which == 4) ? 8 : (which == 9) ? 1 : 4;
    int NT = (which == 1 || which == 2) ? 24 : (which == 3) ? 2 : (which == 6) ? 7 : 8;
    if (idx >= NT * KT * 512) return;
    int j = idx & 7;
    int L = (idx >> 3) & 63;
    int t = idx >> 9;
    int kt = t % KT, nt = t / KT;
    int k = kt * 32 + (L >> 4) * 8 + j;
    int n = nt * 16 + (L & 15);
    switch (which) {
        case 0: rootP[idx] = (half_t)root[k * D + n]; break;
        case 1: WihP[idx] = (half_t)wih[n * D + k]; break;
        case 2: WhhP[idx] = (half_t)whh[n * D + k]; break;
        case 3: bondTP[idx] = (half_t)bond[n * D + k]; break;
        case 4: s1P[idx] = (half_t)sw1[n * 256 + k]; break;
        case 5: s2P[idx] = (half_t)sw2[n * 128 + k]; break;
        case 6: s3P[idx] = (n < OPS) ? (half_t)sw3[n * 128 + k] : (half_t)0.f; break;
        case 7: w1P[idx] = (half_t)bw1[n * D + k]; break;
        case 8: w2P[idx] = (half_t)bw2[n * D + k]; break;
        case 9: bondQP[idx] = (half_t)bond[k * D + n]; break;
    }
}

__global__ void k_deg(const int* __restrict__ eidx, int* __restrict__ deg) {
    int e = blockIdx.x * 256 + threadIdx.x;
    if (e < NEDGES) atomicAdd(&deg[eidx[NEDGES + e]], 1);
}

__global__ void k_scan(const int* __restrict__ deg, int* __restrict__ row_start,
                       float* __restrict__ inv_deg) {
    __shared__ int sums[256];
    int t = threadIdx.x;
    int base = t * 32;
    int s = 0;
    for (int k = 0; k < 32; ++k) s += deg[base + k];
    sums[t] = s;
    __syncthreads();
    for (int off = 1; off < 256; off <<= 1) {
        int v = sums[t];
        int u = (t >= off) ? sums[t - off] : 0;
        __syncthreads();
        sums[t] = v + u;
        __syncthreads();
    }
    int run = sums[t] - s;
    for (int k = 0; k < 32; ++k) {
        int d = deg[base + k];
        row_start[base + k] = run;
        run += d;
        inv_deg[base + k] = (d > 0) ? (1.0f / (float)d) : 0.0f;
    }
    if (t == 255) row_start[NNODES] = run;
}

// CSR-ordered packed edges: epack[pos] = {src, a0, a1, dst}
__global__ void k_scatter(const int* __restrict__ eidx, const int* __restrict__ eattr,
                          const int* __restrict__ row_start,
                          int* __restrict__ fill, int4* __restrict__ epack) {
    int e = blockIdx.x * 256 + threadIdx.x;
    if (e < NEDGES) {
        int d = eidx[NEDGES + e];
        int pos = row_start[d] + atomicAdd(&fill[d], 1);
        int2 aa = *(const int2*)(eattr + 2 * e);
        epack[pos] = make_int4(eidx[e], aa.x, aa.y, d);
    }
}

// ---------------- init (MFMA) + fused P0 ----------------
__global__ __launch_bounds__(512, 2) void k_init(
    const int* __restrict__ x, const float* __restrict__ embBlock,
    const half_t* __restrict__ w1P, const float* __restrict__ b1,
    const half_t* __restrict__ w2P, const float* __restrict__ b2,
    const half_t* __restrict__ bondTP,
    float* __restrict__ hF, float* __restrict__ P0) {
    __shared__ __align__(16) half_t Ae[IMT * LDA];
    __shared__ __align__(16) half_t T1[IMT * LDA];
    const int tid = threadIdx.x;
    const int w = tid >> 6;
    const int lane = tid & 63;
    const int quad = lane >> 4;
    const int l16 = lane & 15;
    const int n0 = blockIdx.x * IMT;
    const int c = w * 16 + l16;

    {
        int row = tid >> 4;
        int col = (tid & 15) * 8;
        const float* src = embBlock + (size_t)x[n0 + row] * D + col;
        float4 v0 = ((const float4*)src)[0];
        float4 v1 = ((const float4*)src)[1];
        f16x8 hv;
        hv[0] = (half_t)v0.x; hv[1] = (half_t)v0.y; hv[2] = (half_t)v0.z; hv[3] = (half_t)v0.w;
        hv[4] = (half_t)v1.x; hv[5] = (half_t)v1.y; hv[6] = (half_t)v1.z; hv[7] = (half_t)v1.w;
        *(f16x8*)&Ae[row * LDA + col] = hv;
    }
    __syncthreads();

    {
        f32x4 acc[2] = {{0.f, 0.f, 0.f, 0.f}, {0.f, 0.f, 0.f, 0.f}};
#pragma unroll
        for (int kt = 0; kt < 4; ++kt) {
            f16x8 b = *(const f16x8*)(w1P + (size_t)((w * 4 + kt) * 64 + lane) * 8);
            f16x8 a0 = *(const f16x8*)&Ae[(0 + l16) * LDA + kt * 32 + quad * 8];
            f16x8 a1 = *(const f16x8*)&Ae[(16 + l16) * LDA + kt * 32 + quad * 8];
            acc[0] = __builtin_amdgcn_mfma_f32_16x16x32_f16(a0, b, acc[0], 0, 0, 0);
            acc[1] = __builtin_amdgcn_mfma_f32_16x16x32_f16(a1, b, acc[1], 0, 0, 0);
        }
        float bb = b1[c];
#pragma unroll
        for (int mt = 0; mt < 2; ++mt)
#pragma unroll
            for (int r = 0; r < 4; ++r)
                T1[(mt * 16 + quad * 4 + r) * LDA + c] = (half_t)leaky(acc[mt][r] + bb);
    }
    __syncthreads();

    {
        f32x4 acc[2] = {{0.f, 0.f, 0.f, 0.f}, {0.f, 0.f, 0.f, 0.f}};
#pragma unroll
        for (int kt = 0; kt < 4; ++kt) {
            f16x8 b = *(const f16x8*)(w2P + (size_t)((w * 4 + kt) * 64 + lane) * 8);
            f16x8 a0 = *(const f16x8*)&T1[(0 + l16) * LDA + kt * 32 + quad * 8];
            f16x8 a1 = *(const f16x8*)&T1[(16 + l16) * LDA + kt * 32 + quad * 8];
            acc[0] = __builtin_amdgcn_mfma_f32_16x16x32_f16(a0, b, acc[0], 0, 0, 0);
            acc[1] = __builtin_amdgcn_mfma_f32_16x16x32_f16(a1, b, acc[1], 0, 0, 0);
        }
        float bb = b2[c];
#pragma unroll
        for (int mt = 0; mt < 2; ++mt)
#pragma unroll
            for (int r = 0; r < 4; ++r) {
                int row = mt * 16 + quad * 4 + r;
                float h = acc[mt][r] + bb;
                hF[(size_t)(n0 + row) * D + c] = h;
                Ae[row * LDA + c] = (half_t)h;
            }
    }
    __syncthreads();

    if (w < 4) {   // P0 = h0 @ bond^T
        int mt = w >> 1, nt = w & 1;
        f32x4 acc = {0.f, 0.f, 0.f, 0.f};
#pragma unroll
        for (int kt = 0; kt < 4; ++kt) {
            f16x8 b = *(const f16x8*)(bondTP + (size_t)((nt * 4 + kt) * 64 + lane) * 8);
            f16x8 a = *(const f16x8*)&Ae[(mt * 16 + l16) * LDA + kt * 32 + quad * 8];
            acc = __builtin_amdgcn_mfma_f32_16x16x32_f16(a, b, acc, 0, 0, 0);
        }
#pragma unroll
        for (int r = 0; r < 4; ++r)
            P0[(size_t)(n0 + mt * 16 + quad * 4 + r) * 32 + nt * 16 + l16] = acc[r];
    }
}

// ---------------- one conv+GRU step ----------------
// 512 blocks x 512 threads (2 blocks/CU, 4 waves/SIMD); block owns 16 nodes;
// wave w owns cols [16w,16w+16). VGPR-capped: only root/agg B-frags prefetch,
// gh/gi B-frags stream inline (latency hidden by co-resident block).
__global__ __launch_bounds__(512, 4) void k_step(
    float* __restrict__ hF,
    const float* __restrict__ Pprev, float* __restrict__ Pnext,
    const half_t* __restrict__ rootP, const half_t* __restrict__ WihP,
    const half_t* __restrict__ WhhP, const half_t* __restrict__ bondTP,
    const half_t* __restrict__ bondQP,
    const float* __restrict__ cbias, const float* __restrict__ bih,
    const float* __restrict__ bhh,
    const int4* __restrict__ epack,
    const int* __restrict__ row_start, const float* __restrict__ inv_deg, int writeP) {
    __shared__ __align__(16) half_t As[MTS * LDA];
    __shared__ __align__(16) half_t Am[MTS * LDA];
    __shared__ __align__(16) float Hs[MTS * LDH];
    __shared__ __align__(16) half_t Qh[MTS * LDQ];
    __shared__ float Q[MTS * 32];

    const int tid = threadIdx.x;
    const int w = tid >> 6;
    const int lane = tid & 63;
    const int quad = lane >> 4;
    const int l16 = lane & 15;
    const int n0 = blockIdx.x * MTS;
    const int c = w * 16 + l16;

    // --- phase A: stage h (one float4/thread), zero Q, edge gather, small prefetch ---
    {
        int row = tid >> 5;
        int col = (tid & 31) * 4;
        float4 v = *(const float4*)(hF + (size_t)(n0 + row) * D + col);
        half_t* dst = &As[row * LDA + col];
        dst[0] = (half_t)v.x; dst[1] = (half_t)v.y; dst[2] = (half_t)v.z; dst[3] = (half_t)v.w;
        *(float4*)&Hs[row * LDH + col] = v;
    }
    if (tid < MTS * 32) Q[tid] = 0.f;
    const int p0 = row_start[n0];
    const int p1 = row_start[n0 + MTS];
    int4 ep;
    float wv = 0.f, idg = 0.f;
    const int pme = p0 + tid;
    const bool have = (pme < p1);
    if (have) {
        ep = epack[pme];
        wv = Pprev[(size_t)ep.x * 32 + ep.y];
        idg = inv_deg[ep.w];
    }
    f16x8 rootB[4];
#pragma unroll
    for (int kt = 0; kt < 4; ++kt)
        rootB[kt] = *(const f16x8*)(rootP + (size_t)((w * 4 + kt) * 64 + lane) * 8);
    f16x8 aggB = *(const f16x8*)(bondQP + (size_t)(w * 64 + lane) * 8);
    const float cb = cbias[c];
    const float bi0 = bih[c], bi1 = bih[D + c], bi2 = bih[2 * D + c];
    const float bh0 = bhh[c], bh1 = bhh[D + c], bh2 = bhh[2 * D + c];
    __syncthreads();

    // --- phase B: conv (prefetched B) + Q atomics + gh GEMM (B streamed) ---
    f32x4 convAcc = {0.f, 0.f, 0.f, 0.f};
#pragma unroll
    for (int kt = 0; kt < 4; ++kt) {
        f16x8 a = *(const f16x8*)&As[l16 * LDA + kt * 32 + quad * 8];
        convAcc = __builtin_amdgcn_mfma_f32_16x16x32_f16(a, rootB[kt], convAcc, 0, 0, 0);
    }
    if (have) atomicAdd(&Q[(ep.w - n0) * 32 + ep.z], wv * idg);
    for (int p2 = pme + 512; p2 < p1; p2 += 512) {
        int4 e2 = epack[p2];
        atomicAdd(&Q[(e2.w - n0) * 32 + e2.z], Pprev[(size_t)e2.x * 32 + e2.y] * inv_deg[e2.w]);
    }
    f32x4 ghA[3] = {{0.f, 0.f, 0.f, 0.f}, {0.f, 0.f, 0.f, 0.f}, {0.f, 0.f, 0.f, 0.f}};
#pragma unroll
    for (int kt = 0; kt < 4; ++kt) {
        f16x8 a = *(const f16x8*)&As[l16 * LDA + kt * 32 + quad * 8];
#pragma unroll
        for (int g = 0; g < 3; ++g) {
            f16x8 b = *(const f16x8*)(WhhP + (size_t)(((g * 8 + w) * 4 + kt) * 64 + lane) * 8);
            ghA[g] = __builtin_amdgcn_mfma_f32_16x16x32_f16(a, b, ghA[g], 0, 0, 0);
        }
    }
    __syncthreads();   // Q complete

    // --- convert Q -> fp16 ---
    if (tid < MTS * 32) Qh[(tid >> 5) * LDQ + (tid & 31)] = (half_t)Q[tid];
    __syncthreads();

    // --- agg MFMA + m -> Am ---
    {
        f32x4 acc = {0.f, 0.f, 0.f, 0.f};
        f16x8 a = *(const f16x8*)&Qh[l16 * LDQ + quad * 8];
        acc = __builtin_amdgcn_mfma_f32_16x16x32_f16(a, aggB, acc, 0, 0, 0);
#pragma unroll
        for (int r = 0; r < 4; ++r) {
            float m = convAcc[r] + cb + acc[r];
            Am[(quad * 4 + r) * LDA + c] = (half_t)leaky(m);
        }
    }
    __syncthreads();

    // --- gi GEMM (B streamed) + GRU combine ---
    f32x4 giA[3] = {{0.f, 0.f, 0.f, 0.f}, {0.f, 0.f, 0.f, 0.f}, {0.f, 0.f, 0.f, 0.f}};
#pragma unroll
    for (int kt = 0; kt < 4; ++kt) {
        f16x8 a = *(const f16x8*)&Am[l16 * LDA + kt * 32 + quad * 8];
#pragma unroll
        for (int g = 0; g < 3; ++g) {
            f16x8 b = *(const f16x8*)(WihP + (size_t)(((g * 8 + w) * 4 + kt) * 64 + lane) * 8);
            giA[g] = __builtin_amdgcn_mfma_f32_16x16x32_f16(a, b, giA[g], 0, 0, 0);
        }
    }
#pragma unroll
    for (int r = 0; r < 4; ++r) {
        int row = quad * 4 + r;
        float rg = fast_sigmoid(giA[0][r] + bi0 + ghA[0][r] + bh0);
        float z = fast_sigmoid(giA[1][r] + bi1 + ghA[1][r] + bh1);
        float nn = fast_tanh(giA[2][r] + bi2 + rg * (ghA[2][r] + bh2));
        float hnew = (1.f - z) * nn + z * Hs[row * LDH + c];
        hF[(size_t)(n0 + row) * D + c] = hnew;
        As[row * LDA + c] = (half_t)hnew;
    }

    if (writeP) {
        __syncthreads();
        if (w < 2) {   // P tile: 16 rows x 32 cols, nt = w
            f32x4 acc = {0.f, 0.f, 0.f, 0.f};
#pragma unroll
            for (int kt = 0; kt < 4; ++kt) {
                f16x8 b = *(const f16x8*)(bondTP + (size_t)((w * 4 + kt) * 64 + lane) * 8);
                f16x8 a = *(const f16x8*)&As[l16 * LDA + kt * 32 + quad * 8];
                acc = __builtin_amdgcn_mfma_f32_16x16x32_f16(a, b, acc, 0, 0, 0);
            }
#pragma unroll
            for (int r = 0; r < 4; ++r)
                Pnext[(size_t)(n0 + quad * 4 + r) * 32 + w * 16 + l16] = acc[r];
        }
    }
}

// ---------------- stem head (MFMA) + fused gpred ----------------
__device__ __forceinline__ int lower_bound_dev(const int* a, int n, int v) {
    int lo = 0, hi = n;
    while (lo < hi) {
        int m = (lo + hi) >> 1;
        if (a[m] < v) lo = m + 1;
        else hi = m;
    }
    return lo;
}

__global__ __launch_bounds__(512) void k_heads(
    const float* __restrict__ hF, const int* __restrict__ sni, const int* __restrict__ stypes,
    const float* __restrict__ embStem,
    const half_t* __restrict__ s1P, const float* __restrict__ b1,
    const half_t* __restrict__ s2P, const float* __restrict__ b2,
    const half_t* __restrict__ s3P, const float* __restrict__ b3,
    const int* __restrict__ batch,
    const float* __restrict__ g1T, const float* __restrict__ gb1,
    const float* __restrict__ gw2, const float* __restrict__ gb2,
    float* __restrict__ dout) {
    __shared__ __align__(16) half_t cat[16 * LDA2];
    __shared__ __align__(16) half_t t1[16 * LDA];
    __shared__ __align__(16) half_t t2[16 * LDA];
    const int tid = threadIdx.x;
    if (blockIdx.x >= 256) {
        int g = blockIdx.x - 256;
        if (tid >= 128) return;
        __shared__ float mean_s[D];
        __shared__ float red[D];
        int j = tid;
        int lo = lower_bound_dev(batch, NNODES, g);
        int hi = lower_bound_dev(batch, NNODES, g + 1);
        float sum = 0.f;
        for (int n = lo; n < hi; ++n) sum += hF[(size_t)n * D + j];
        float denom = (hi > lo) ? (float)(hi - lo) : 1.0f;
        mean_s[j] = sum / denom;
        __syncthreads();
        float a = gb1[j];
        for (int i = 0; i < D; ++i) a += mean_s[i] * g1T[i * D + j];
        a = leaky(a);
        red[j] = a * gw2[j];
        __syncthreads();
        for (int off = 64; off > 0; off >>= 1) {
            if (j < off) red[j] += red[j + off];
            __syncthreads();
        }
        if (j == 0) dout[NSTEMS * OPS + g] = red[0] + gb2[0];
        return;
    }
    const int w = tid >> 6;
    const int lane = tid & 63;
    const int quad = lane >> 4;
    const int l16 = lane & 15;
    const int s0 = blockIdx.x * 16;
    const int c = w * 16 + l16;

    {
        int row = tid >> 5;
        int col = (tid & 31) * 8;
        const float* src;
        if (col < D) src = hF + (size_t)sni[s0 + row] * D + col;
        else src = embStem + (size_t)stypes[s0 + row] * D + (col - D);
        float4 v0 = ((const float4*)src)[0];
        float4 v1 = ((const float4*)src)[1];
        f16x8 hv;
        hv[0] = (half_t)v0.x; hv[1] = (half_t)v0.y; hv[2] = (half_t)v0.z; hv[3] = (half_t)v0.w;
        hv[4] = (half_t)v1.x; hv[5] = (half_t)v1.y; hv[6] = (half_t)v1.z; hv[7] = (half_t)v1.w;
        *(f16x8*)&cat[row * LDA2 + col] = hv;
    }
    __syncthreads();

    {
        f32x4 acc = {0.f, 0.f, 0.f, 0.f};
#pragma unroll
        for (int kt = 0; kt < 8; ++kt) {
            f16x8 b = *(const f16x8*)(s1P + (size_t)((w * 8 + kt) * 64 + lane) * 8);
            f16x8 a = *(const f16x8*)&cat[l16 * LDA2 + kt * 32 + quad * 8];
            acc = __builtin_amdgcn_mfma_f32_16x16x32_f16(a, b, acc, 0, 0, 0);
        }
        float bb = b1[c];
#pragma unroll
        for (int r = 0; r < 4; ++r)
            t1[(quad * 4 + r) * LDA + c] = (half_t)leaky(acc[r] + bb);
    }
    __syncthreads();
    {
        f32x4 acc = {0.f, 0.f, 0.f, 0.f};
#pragma unroll
        for (int kt = 0; kt < 4; ++kt) {
            f16x8 b = *(const f16x8*)(s2P + (size_t)((w * 4 + kt) * 64 + lane) * 8);
            f16x8 a = *(const f16x8*)&t1[l16 * LDA + kt * 32 + quad * 8];
            acc = __builtin_amdgcn_mfma_f32_16x16x32_f16(a, b, acc, 0, 0, 0);
        }
        float bb = b2[c];
#pragma unroll
        for (int r = 0; r < 4; ++r)
            t2[(quad * 4 + r) * LDA + c] = (half_t)leaky(acc[r] + bb);
    }
    __syncthreads();
    if (w < 7) {
        f32x4 acc = {0.f, 0.f, 0.f, 0.f};
#pragma unroll
        for (int kt = 0; kt < 4; ++kt) {
            f16x8 b = *(const f16x8*)(s3P + (size_t)((w * 4 + kt) * 64 + lane) * 8);
            f16x8 a = *(const f16x8*)&t2[l16 * LDA + kt * 32 + quad * 8];
            acc = __builtin_amdgcn_mfma_f32_16x16x32_f16(a, b, acc, 0, 0, 0);
        }
        int j = w * 16 + l16;
        if (j < OPS) {
            float bb = b3[j];
#pragma unroll
            for (int r = 0; r < 4; ++r)
                dout[(size_t)(s0 + quad * 4 + r) * OPS + j] = acc[r] + bb;
        }
    }
}

// ---------------- launch ----------------
extern "C" void kernel_launch(void* const* d_in, const int* in_sizes, int n_in,
                              void* d_out, int out_size, void* d_ws, size_t ws_size,
                              hipStream_t stream) {
    const int* x = (const int*)d_in[0];
    const int* stypes = (const int*)d_in[1];
    const int* eattr = (const int*)d_in[2];
    const int* eidx = (const int*)d_in[3];
    const int* sni = (const int*)d_in[4];
    const int* batch = (const int*)d_in[5];
    const float* embBlock = (const float*)d_in[6];
    const float* embStem = (const float*)d_in[7];
    const float* embBond = (const float*)d_in[8];
    const float* b2e_w1 = (const float*)d_in[9];
    const float* b2e_b1 = (const float*)d_in[10];
    const float* b2e_w2 = (const float*)d_in[11];
    const float* b2e_b2 = (const float*)d_in[12];
    const float* conv_root = (const float*)d_in[13];
    const float* conv_bias = (const float*)d_in[14];
    const float* gru_w_ih = (const float*)d_in[15];
    const float* gru_w_hh = (const float*)d_in[16];
    const float* gru_b_ih = (const float*)d_in[17];
    const float* gru_b_hh = (const float*)d_in[18];
    const float* s2p_w1 = (const float*)d_in[19];
    const float* s2p_b1 = (const float*)d_in[20];
    const float* s2p_w2 = (const float*)d_in[21];
    const float* s2p_b2 = (const float*)d_in[22];
    const float* s2p_w3 = (const float*)d_in[23];
    const float* s2p_b3 = (const float*)d_in[24];
    const float* g2p_w1 = (const float*)d_in[25];
    const float* g2p_b1 = (const float*)d_in[26];
    const float* g2p_w2 = (const float*)d_in[27];
    const float* g2p_b2 = (const float*)d_in[28];
    float* out_f = (float*)d_out;

    float* W = (float*)d_ws;
    size_t off = 0;
    auto alloc = [&](size_t words) {
        size_t o = off;
        off += (words + 3) & ~(size_t)3;
        return o;
    };
    float* hF = W + alloc(NNODES * D);
    float* P0 = W + alloc(NNODES * 32);
    float* P1 = W + alloc(NNODES * 32);
    half_t* rootP = (half_t*)(W + alloc(16384 / 2));
    half_t* WihP = (half_t*)(W + alloc(49152 / 2));
    half_t* WhhP = (half_t*)(W + alloc(49152 / 2));
    half_t* bondTP = (half_t*)(W + alloc(4096 / 2));
    half_t* s1P = (half_t*)(W + alloc(32768 / 2));
    half_t* s2P = (half_t*)(W + alloc(16384 / 2));
    half_t* s3P = (half_t*)(W + alloc(14336 / 2));
    half_t* w1P = (half_t*)(W + alloc(16384 / 2));
    half_t* w2P = (half_t*)(W + alloc(16384 / 2));
    half_t* bondQP = (half_t*)(W + alloc(4096 / 2));
    float* g1T = W + alloc(128 * 128);
    int* row_start = (int*)(W + alloc(NNODES + 1));
    int4* epack = (int4*)(W + alloc(NEDGES * 4));
    float* inv_deg = W + alloc(NNODES);
    float* zbase = W + alloc(2 * NNODES);   // deg + fill
    int* deg = (int*)zbase;
    int* fill = deg + NNODES;

    k_setup<<<dim3(192, 12), 256, 0, stream>>>(
        conv_root, gru_w_ih, gru_w_hh, embBond, s2p_w1, s2p_w2, s2p_w3,
        b2e_w1, b2e_w2, g2p_w1,
        rootP, WihP, WhhP, bondTP, s1P, s2P, s3P, w1P, w2P, bondQP,
        g1T, (int*)zbase);
    k_deg<<<(NEDGES + 255) / 256, 256, 0, stream>>>(eidx, deg);
    k_scan<<<1, 256, 0, stream>>>(deg, row_start, inv_deg);
    k_scatter<<<(NEDGES + 255) / 256, 256, 0, stream>>>(eidx, eattr, row_start, fill, epack);
    k_init<<<NNODES / IMT, 512, 0, stream>>>(x, embBlock, w1P, b2e_b1, w2P, b2e_b2,
                                             bondTP, hF, P0);

    for (int step = 0; step < NSTEPS; ++step) {
        const float* Pprev = (step & 1) ? P1 : P0;
        float* Pnext = (step & 1) ? P0 : P1;
        int writeP = (step < NSTEPS - 1) ? 1 : 0;
        k_step<<<NBS, 512, 0, stream>>>(
            hF, Pprev, Pnext, rootP, WihP, WhhP, bondTP, bondQP,
            conv_bias, gru_b_ih, gru_b_hh,
            epack, row_start, inv_deg, writeP);
    }

    k_heads<<<NSTEMS / 16 + NGRAPHS, 512, 0, stream>>>(
        hF, sni, stypes, embStem,
        s1P, s2p_b1, s2P, s2p_b2, s3P, s2p_b3,
        batch, g1T, g2p_b1, g2p_w2, g2p_b2, out_f);
}